// Round 11
// baseline (193.521 us; speedup 1.0000x reference)
//
#include <hip/hip_runtime.h>
#include <stdint.h>

#define B_ 4
#define N_ 2048
#define T_ 8
#define NL_ 64
#define DIM_ 1024
#define H_ 16
#define HD_ 64
#define TN_ (T_*NL_)   // 512

typedef __bf16 bf16x8 __attribute__((ext_vector_type(8)));
typedef float f32x4 __attribute__((ext_vector_type(4)));

__device__ __forceinline__ float b2f(unsigned short x) {
  union { uint32_t u; float f; } v; v.u = ((uint32_t)x) << 16; return v.f;
}
__device__ __forceinline__ unsigned short f2b(float f) {
  union { float f; uint32_t u; } v; v.f = f;
  uint32_t r = v.u + 0x7FFFu + ((v.u >> 16) & 1u);
  return (unsigned short)(r >> 16);
}

// direct HBM->LDS DMA, 16B per lane (global_load_lds_dwordx4), m104 contract.
__device__ __forceinline__ void gload_lds16(const unsigned short* g, unsigned short* l) {
  __builtin_amdgcn_global_load_lds(
      (const __attribute__((address_space(1))) uint32_t*)g,
      (__attribute__((address_space(3))) uint32_t*)l, 16, 0, 0);
}

// wave-local LDS fence (rule 18): drain ds ops + pin scheduler.
#define WAVE_LDS_FENCE() do { \
    asm volatile("s_waitcnt lgkmcnt(0)" ::: "memory"); \
    __builtin_amdgcn_sched_barrier(0); \
  } while (0)

// per-wave fp32-vs-bf16 storage detection (validated rounds 5-10).
__device__ __forceinline__ bool detect_isf(const unsigned short* text, int t) {
  int l = t & 63;
  int bad = 0;
  #pragma unroll
  for (int i = 0; i < 16; i++) {
    unsigned short w = text[l * 16 + i];
    int e = (w >> 7) & 0xFF;
    if (e != 0 && (e < 90 || e > 150)) bad++;
  }
  #pragma unroll
  for (int off = 32; off > 0; off >>= 1) bad += __shfl_xor(bad, off);
  return bad > 64;
}

// ================= prep1 (256t): media cast + bo cast + wkv transpose ==========
// blocks [0,2048): media; 2048: bo; [2049,4097): wkv transpose (kv prerequisites
// live here so prep2's kv-GEMM can consume them next launch).
__global__ __launch_bounds__(256) void prep1_kernel(
    const void* __restrict__ text,
    const void* __restrict__ media, unsigned short* __restrict__ mb,
    const void* __restrict__ bo, unsigned short* __restrict__ bob,
    const void* __restrict__ wkv, unsigned short* __restrict__ wkvt) {
  __shared__ __align__(16) unsigned short tile[32][33];
  int gb = blockIdx.x;
  int t = threadIdx.x;
  bool isf = detect_isf((const unsigned short*)text, t);

  if (gb < 2048) {                            // ---- media cast ----
    int i = gb * 256 + t;                     // < 524288 = N4M exactly
    ushort4 o;
    if (isf) {
      float4 v = ((const float4*)media)[i];
      o.x = f2b(v.x); o.y = f2b(v.y); o.z = f2b(v.z); o.w = f2b(v.w);
    } else {
      o = ((const ushort4*)media)[i];
    }
    ((ushort4*)mb)[i] = o;
    return;
  }
  if (gb == 2048) {                           // ---- bo cast ----
    int j = t;                                // DIM_/4 = 256
    ushort4 o;
    if (isf) {
      float4 v = ((const float4*)bo)[j];
      o.x = f2b(v.x); o.y = f2b(v.y); o.z = f2b(v.z); o.w = f2b(v.w);
    } else {
      o = ((const ushort4*)bo)[j];
    }
    ((ushort4*)bob)[j] = o;
    return;
  }
  {                                           // ---- wkv transpose+cast ----
    int zz = gb - 2049;                       // 0..2047, C=2048, nx=64
    const int C = 2048, R = 1024;
    int xi = zz & 63, yi = zz >> 6;
    int bx = xi * 32, by = yi * 32;
    int x = t & 31, y = t >> 5;               // y 0..7, stride 8
    if (isf) {
      const float* s = (const float*)wkv;
      for (int i = y; i < 32; i += 8) tile[i][x] = f2b(s[(size_t)(by + i) * C + bx + x]);
    } else {
      const unsigned short* s = (const unsigned short*)wkv;
      for (int i = y; i < 32; i += 8) tile[i][x] = s[(size_t)(by + i) * C + bx + x];
    }
    __syncthreads();
    for (int i = y; i < 32; i += 8) wkvt[(size_t)(bx + i) * R + by + x] = tile[x][i];
  }
}

// ---------------- 256x128 MFMA GEMM core (round-10 verified), smem param -------
__device__ __forceinline__ void gemm256_core(const unsigned short* __restrict__ A,
                                             const unsigned short* __restrict__ Bt,
                                             unsigned short* __restrict__ C,
                                             float* __restrict__ Cf,
                                             const unsigned short* __restrict__ bias,
                                             int bid, int mtiles, int M, int N, int K,
                                             bool f32o, int t, unsigned char* smem) {
  typedef unsigned short ldsA_t[256][32];
  typedef unsigned short ldsB_t[128][32];
  ldsA_t* As = (ldsA_t*)smem;
  ldsB_t* Bs = (ldsB_t*)(smem + 49152);
  int m0 = (bid % mtiles) * 256, n0 = (bid / mtiles) * 128;
  int wave = t >> 6, lane = t & 63;
  int wr = wave >> 1, wc = wave & 1;
  f32x4 acc[4][4];
  #pragma unroll
  for (int i = 0; i < 4; i++)
    #pragma unroll
    for (int j = 0; j < 4; j++)
      #pragma unroll
      for (int r = 0; r < 4; r++) acc[i][j][r] = 0.f;
  int lr = lane & 15;
  int lk = (((lane >> 4) ^ ((lr >> 2) & 3)) & 3) * 8;
  int rowA0 = t >> 2, rowA1 = rowA0 + 128, rowB = rowA0;
  int kcp = (t & 3) * 8;
  int kg  = (((t & 3) ^ ((rowA0 >> 2) & 3)) & 3) * 8;
  const unsigned short* aA0 = A  + (size_t)(m0 + rowA0) * K + kg;
  const unsigned short* aA1 = A  + (size_t)(m0 + rowA1) * K + kg;
  const unsigned short* bB  = Bt + (size_t)(n0 + rowB)  * K + kg;
#define STAGE_(buf, koff) do { \
    gload_lds16(aA0 + (koff), &As[buf][rowA0][kcp]); \
    gload_lds16(aA1 + (koff), &As[buf][rowA1][kcp]); \
    gload_lds16(bB  + (koff), &Bs[buf][rowB][kcp]); \
  } while (0)
  STAGE_(0, 0);
  STAGE_(1, 32);
  asm volatile("s_waitcnt vmcnt(3)" ::: "memory");
  __builtin_amdgcn_s_barrier();
  int cur = 0;
  for (int k0 = 0; k0 < K; k0 += 32) {
    bf16x8 af[4], bfr[4];
    #pragma unroll
    for (int i = 0; i < 4; i++) af[i]  = *(const bf16x8*)(&As[cur][wr * 64 + i * 16 + lr][lk]);
    #pragma unroll
    for (int j = 0; j < 4; j++) bfr[j] = *(const bf16x8*)(&Bs[cur][wc * 64 + j * 16 + lr][lk]);
    asm volatile("s_waitcnt lgkmcnt(0)" ::: "memory");
    __builtin_amdgcn_sched_barrier(0);
    if (k0 + 64 < K) {
      int nb2 = cur + 2; if (nb2 >= 3) nb2 -= 3;
      STAGE_(nb2, k0 + 64);
      __builtin_amdgcn_sched_barrier(0);
    }
    #pragma unroll
    for (int i = 0; i < 4; i++)
      #pragma unroll
      for (int j = 0; j < 4; j++)
        acc[i][j] = __builtin_amdgcn_mfma_f32_16x16x32_bf16(af[i], bfr[j], acc[i][j], 0, 0, 0);
    if (k0 + 64 < K) {
      asm volatile("s_waitcnt vmcnt(3)" ::: "memory");
    } else if (k0 + 32 < K) {
      asm volatile("s_waitcnt vmcnt(0)" ::: "memory");
    }
    __builtin_amdgcn_s_barrier();
    cur = (cur == 2) ? 0 : cur + 1;
  }
#undef STAGE_
  int rbase = (lane >> 4) * 4;
  int cbase = lane & 15;
  #pragma unroll
  for (int i = 0; i < 4; i++) {
    #pragma unroll
    for (int j = 0; j < 4; j++) {
      int row = m0 + wr * 64 + i * 16 + rbase;
      int col = n0 + wc * 64 + j * 16 + cbase;
      float bv = bias ? b2f(bias[col]) : 0.f;
      if (f32o) {
        #pragma unroll
        for (int r = 0; r < 4; r++)
          Cf[(size_t)(row + r) * N + col] = acc[i][j][r] + bv;
      } else {
        #pragma unroll
        for (int r = 0; r < 4; r++)
          C[(size_t)(row + r) * N + col] = f2b(acc[i][j][r] + bv);
      }
    }
  }
}

// ================= prep2 (512t): times + kv-GEMM + LN + wq/wo transposes =======
// blocks [0,4) times; [4,132) kv-GEMM (inputs from prep1); [132,1156) LN
// (8 rows/block, wave-per-row); [1156,2180) wq transpose; [2180,3204) wo.
__global__ __launch_bounds__(512) void prep2_kernel(
    const void* __restrict__ text, const void* __restrict__ locs,
    int* __restrict__ tt,
    const void* __restrict__ lng, const void* __restrict__ lnb,
    unsigned short* __restrict__ tn,
    const unsigned short* __restrict__ mb, const unsigned short* __restrict__ wkvt,
    unsigned short* __restrict__ kvb,
    const void* __restrict__ wq, unsigned short* __restrict__ wqt,
    const void* __restrict__ wo, unsigned short* __restrict__ wot) {
  __shared__ __align__(16) unsigned char SMEM[73728];
  int gb = blockIdx.x;
  int t = threadIdx.x;

  if (gb < 4) {                               // ---- times (512-thread scan) ----
    int* red = (int*)SMEM;
    int b = gb;
    const unsigned char* p8 = (const unsigned char*)locs;
    const int* p32 = (const int*)locs;
    int cnt = 0;
    for (int i = t; i < B_*N_; i += 512) cnt += (p8[i] != 0) ? 1 : 0;
    red[t] = cnt;
    __syncthreads();
    for (int off = 256; off > 0; off >>= 1) {
      if (t < off) red[t] += red[t + off];
      __syncthreads();
    }
    int total = red[0];
    __syncthreads();
    bool isb = (total >= 2 * T_);
    int x[4];
    int base = b * N_ + t * 4;
    if (isb) {
      #pragma unroll
      for (int i = 0; i < 4; i++) x[i] = (int)(p8[base + i] != 0);
    } else {
      #pragma unroll
      for (int i = 0; i < 4; i++) x[i] = (int)(p32[base + i] != 0);
    }
    #pragma unroll
    for (int i = 1; i < 4; i++) x[i] += x[i-1];
    int tot = x[3];
    red[t] = tot;
    __syncthreads();
    for (int off = 1; off < 512; off <<= 1) {
      int v = (t >= off) ? red[t - off] : 0;
      __syncthreads();
      red[t] += v;
      __syncthreads();
    }
    int excl = red[t] - tot;
    #pragma unroll
    for (int i = 0; i < 4; i++) tt[base + i] = excl + x[i];
    return;
  }
  gb -= 4;

  if (gb < 128) {                             // ---- kv-GEMM (mb @ wkvt^T) ----
    gemm256_core(mb, wkvt, kvb, nullptr, nullptr, gb, 8,
                 B_ * TN_, 2 * DIM_, DIM_, false, t, SMEM);
    return;
  }
  gb -= 128;

  bool isf = detect_isf((const unsigned short*)text, t);

  if (gb < 1024) {                            // ---- LayerNorm: wave per row ----
    int row = gb * 8 + (t >> 6);
    int l = t & 63;
    float f[16], gv_[16], cv_[16];
    if (isf) {
      const float4* x4 = (const float4*)text + (size_t)row * 256;
      const float4* g4 = (const float4*)lng;
      const float4* b4 = (const float4*)lnb;
      #pragma unroll
      for (int j = 0; j < 4; j++) {
        float4 xv = x4[l + 64*j];
        float4 gg = g4[l + 64*j];
        float4 bb = b4[l + 64*j];
        f[4*j+0]=xv.x; f[4*j+1]=xv.y; f[4*j+2]=xv.z; f[4*j+3]=xv.w;
        gv_[4*j+0]=gg.x; gv_[4*j+1]=gg.y; gv_[4*j+2]=gg.z; gv_[4*j+3]=gg.w;
        cv_[4*j+0]=bb.x; cv_[4*j+1]=bb.y; cv_[4*j+2]=bb.z; cv_[4*j+3]=bb.w;
      }
    } else {
      const ushort4* x4 = (const ushort4*)text + (size_t)row * 256;
      const ushort4* g4 = (const ushort4*)lng;
      const ushort4* b4 = (const ushort4*)lnb;
      #pragma unroll
      for (int j = 0; j < 4; j++) {
        ushort4 xv = x4[l + 64*j];
        ushort4 gg = g4[l + 64*j];
        ushort4 bb = b4[l + 64*j];
        f[4*j+0]=b2f(xv.x); f[4*j+1]=b2f(xv.y); f[4*j+2]=b2f(xv.z); f[4*j+3]=b2f(xv.w);
        gv_[4*j+0]=b2f(gg.x); gv_[4*j+1]=b2f(gg.y); gv_[4*j+2]=b2f(gg.z); gv_[4*j+3]=b2f(gg.w);
        cv_[4*j+0]=b2f(bb.x); cv_[4*j+1]=b2f(bb.y); cv_[4*j+2]=b2f(bb.z); cv_[4*j+3]=b2f(bb.w);
      }
    }
    float s = 0.f, s2 = 0.f;
    #pragma unroll
    for (int i = 0; i < 16; i++) { s += f[i]; s2 += f[i]*f[i]; }
    #pragma unroll
    for (int off = 32; off > 0; off >>= 1) { s += __shfl_xor(s, off); s2 += __shfl_xor(s2, off); }
    float mean = s * (1.0f / DIM_);
    float var  = s2 * (1.0f / DIM_) - mean * mean;
    float rs = rsqrtf(var + 1e-5f);
    ushort4* o4 = (ushort4*)(tn + (size_t)row * DIM_);
    #pragma unroll
    for (int j = 0; j < 4; j++) {
      ushort4 o;
      o.x = f2b((f[4*j+0] - mean) * rs * gv_[4*j+0] + cv_[4*j+0]);
      o.y = f2b((f[4*j+1] - mean) * rs * gv_[4*j+1] + cv_[4*j+1]);
      o.z = f2b((f[4*j+2] - mean) * rs * gv_[4*j+2] + cv_[4*j+2]);
      o.w = f2b((f[4*j+3] - mean) * rs * gv_[4*j+3] + cv_[4*j+3]);
      o4[l + 64*j] = o;
    }
    return;
  }
  gb -= 1024;

  {                                           // ---- wq / wo transpose+cast ----
    unsigned short (*tile)[33] = (unsigned short (*)[33])SMEM;
    const void* src; unsigned short* dst; int zz;
    if (gb < 1024) { src = wq; dst = wqt; zz = gb; }
    else           { src = wo; dst = wot; zz = gb - 1024; }
    const int C = 1024, R = 1024;
    int xi = zz & 31, yi = zz >> 5;
    int bx = xi * 32, by = yi * 32;
    int x = t & 31, y = t >> 5;               // y 0..15, stride 16
    if (isf) {
      const float* s = (const float*)src;
      for (int i = y; i < 32; i += 16) tile[i][x] = f2b(s[(size_t)(by + i) * C + bx + x]);
    } else {
      const unsigned short* s = (const unsigned short*)src;
      for (int i = y; i < 32; i += 16) tile[i][x] = s[(size_t)(by + i) * C + bx + x];
    }
    __syncthreads();
    for (int i = y; i < 32; i += 16) dst[(size_t)(bx + i) * R + by + x] = tile[x][i];
  }
}

// ================= fused q-GEMM + attention (256 blocks, 512t) =================
// Phase A: q-tile 256x128 = tn @ wqt^T (round-10 pipeline), acc kept in regs.
// Phase B: each wave's acc IS one attention task's Q (64 rows x head n0/64+wc).
// acc -> per-wave LDS [64][72] (bf16) -> aQ frags -> QK^T -> softmax -> PV -> ao.
// No qb round-trip; 2048 tasks = 256 blocks x 8 waves, zero redundancy.
__global__ __launch_bounds__(512, 4) void qattn_kernel(
    const unsigned short* __restrict__ tn, const unsigned short* __restrict__ wqt,
    const unsigned short* __restrict__ kv, const int* __restrict__ tt,
    unsigned short* __restrict__ ao) {
  __shared__ __align__(16) unsigned char SMEM[73728];
  typedef unsigned short ldsA_t[256][32];
  typedef unsigned short ldsB_t[128][32];
  ldsA_t* As = (ldsA_t*)SMEM;
  ldsB_t* Bs = (ldsB_t*)(SMEM + 49152);
  const int K = DIM_;
  int t = threadIdx.x;
  int bid = blockIdx.x;
  int m0 = (bid & 31) * 256, n0 = (bid >> 5) * 128;   // m-fastest (XCD locality)
  int wave = t >> 6, lane = t & 63;
  int wr = wave >> 1, wc = wave & 1;
  f32x4 acc[4][4];
  #pragma unroll
  for (int i = 0; i < 4; i++)
    #pragma unroll
    for (int j = 0; j < 4; j++)
      #pragma unroll
      for (int r = 0; r < 4; r++) acc[i][j][r] = 0.f;
  int lr = lane & 15;
  int lk = (((lane >> 4) ^ ((lr >> 2) & 3)) & 3) * 8;
  int rowA0 = t >> 2, rowA1 = rowA0 + 128, rowB = rowA0;
  int kcp = (t & 3) * 8;
  int kg  = (((t & 3) ^ ((rowA0 >> 2) & 3)) & 3) * 8;
  const unsigned short* aA0 = tn  + (size_t)(m0 + rowA0) * K + kg;
  const unsigned short* aA1 = tn  + (size_t)(m0 + rowA1) * K + kg;
  const unsigned short* bB  = wqt + (size_t)(n0 + rowB)  * K + kg;
#define STAGE_(buf, koff) do { \
    gload_lds16(aA0 + (koff), &As[buf][rowA0][kcp]); \
    gload_lds16(aA1 + (koff), &As[buf][rowA1][kcp]); \
    gload_lds16(bB  + (koff), &Bs[buf][rowB][kcp]); \
  } while (0)
  STAGE_(0, 0);
  STAGE_(1, 32);
  asm volatile("s_waitcnt vmcnt(3)" ::: "memory");
  __builtin_amdgcn_s_barrier();
  int cur = 0;
  for (int k0 = 0; k0 < K; k0 += 32) {
    bf16x8 af[4], bfr[4];
    #pragma unroll
    for (int i = 0; i < 4; i++) af[i]  = *(const bf16x8*)(&As[cur][wr * 64 + i * 16 + lr][lk]);
    #pragma unroll
    for (int j = 0; j < 4; j++) bfr[j] = *(const bf16x8*)(&Bs[cur][wc * 64 + j * 16 + lr][lk]);
    asm volatile("s_waitcnt lgkmcnt(0)" ::: "memory");
    __builtin_amdgcn_sched_barrier(0);
    if (k0 + 64 < K) {
      int nb2 = cur + 2; if (nb2 >= 3) nb2 -= 3;
      STAGE_(nb2, k0 + 64);
      __builtin_amdgcn_sched_barrier(0);
    }
    #pragma unroll
    for (int i = 0; i < 4; i++)
      #pragma unroll
      for (int j = 0; j < 4; j++)
        acc[i][j] = __builtin_amdgcn_mfma_f32_16x16x32_bf16(af[i], bfr[j], acc[i][j], 0, 0, 0);
    if (k0 + 64 < K) {
      asm volatile("s_waitcnt vmcnt(3)" ::: "memory");
    } else if (k0 + 32 < K) {
      asm volatile("s_waitcnt vmcnt(0)" ::: "memory");
    }
    __builtin_amdgcn_s_barrier();              // final barrier: all LDS reads done
    cur = (cur == 2) ? 0 : cur + 1;
  }
#undef STAGE_
  // ---------------- phase B: per-wave attention ----------------
  unsigned short (*Q)[72] = (unsigned short (*)[72])(SMEM + wave * 9216);
  int rbase = (lane >> 4) * 4;
  int cbase = lane & 15;
  #pragma unroll
  for (int i = 0; i < 4; i++)
    #pragma unroll
    for (int j = 0; j < 4; j++)
      #pragma unroll
      for (int r = 0; r < 4; r++)
        Q[i * 16 + rbase + r][j * 16 + cbase] = f2b(acc[i][j][r]);
  WAVE_LDS_FENCE();

  int g = lane >> 4, g8 = g * 8;
  bf16x8 aQ[2][4];
  #pragma unroll
  for (int ks = 0; ks < 2; ks++)
    #pragma unroll
    for (int mi = 0; mi < 4; mi++)
      aQ[ks][mi] = *(const bf16x8*)(&Q[mi * 16 + lr][ks * 32 + g8]);
  WAVE_LDS_FENCE();                           // Q reads done -> buffer reusable
  unsigned short (*Ps)[72] = Q;

  int h = (n0 >> 6) + wc;
  int bn0 = m0 + wr * 64;
  int tv = tt[bn0];                           // tile-uniform (times step = 256 rows)
  float vmul = (tv >= 1 && tv <= T_) ? 1.f : 0.f;
  int tvc = tv < 1 ? 1 : (tv > T_ ? T_ : tv);
  int b = bn0 >> 11;                          // N_ = 2048
  int kvrow0 = b * TN_ + (tvc - 1) * NL_;

  f32x4 S[4][4];
  #pragma unroll
  for (int i = 0; i < 4; i++)
    #pragma unroll
    for (int j = 0; j < 4; j++)
      #pragma unroll
      for (int r = 0; r < 4; r++) S[i][j][r] = 0.f;
  #pragma unroll
  for (int ks = 0; ks < 2; ks++) {
    bf16x8 bK[4];
    #pragma unroll
    for (int ni = 0; ni < 4; ni++)
      bK[ni] = *(const bf16x8*)(kv + (size_t)(kvrow0 + ni * 16 + lr) * (2 * DIM_) + h * HD_ + ks * 32 + g8);
    #pragma unroll
    for (int mi = 0; mi < 4; mi++)
      #pragma unroll
      for (int ni = 0; ni < 4; ni++)
        S[mi][ni] = __builtin_amdgcn_mfma_f32_16x16x32_bf16(aQ[ks][mi], bK[ni], S[mi][ni], 0, 0, 0);
  }

  #pragma unroll
  for (int mi = 0; mi < 4; mi++) {
    #pragma unroll
    for (int r = 0; r < 4; r++) {
      float mx = fmaxf(fmaxf(S[mi][0][r], S[mi][1][r]), fmaxf(S[mi][2][r], S[mi][3][r]));
      mx = fmaxf(mx, __shfl_xor(mx, 1));
      mx = fmaxf(mx, __shfl_xor(mx, 2));
      mx = fmaxf(mx, __shfl_xor(mx, 4));
      mx = fmaxf(mx, __shfl_xor(mx, 8));
      float e0 = __expf(S[mi][0][r] - mx);
      float e1 = __expf(S[mi][1][r] - mx);
      float e2 = __expf(S[mi][2][r] - mx);
      float e3 = __expf(S[mi][3][r] - mx);
      float sum = e0 + e1 + e2 + e3;
      sum += __shfl_xor(sum, 1);
      sum += __shfl_xor(sum, 2);
      sum += __shfl_xor(sum, 4);
      sum += __shfl_xor(sum, 8);
      float inv = 1.f / sum;
      int qrow = mi * 16 + g * 4 + r;
      Ps[qrow][ 0 + lr] = f2b(e0 * inv);
      Ps[qrow][16 + lr] = f2b(e1 * inv);
      Ps[qrow][32 + lr] = f2b(e2 * inv);
      Ps[qrow][48 + lr] = f2b(e3 * inv);
    }
  }
  WAVE_LDS_FENCE();

  f32x4 O[4][4];
  #pragma unroll
  for (int i = 0; i < 4; i++)
    #pragma unroll
    for (int j = 0; j < 4; j++)
      #pragma unroll
      for (int r = 0; r < 4; r++) O[i][j][r] = 0.f;
  const unsigned short* vb = kv + (size_t)kvrow0 * (2 * DIM_) + DIM_ + h * HD_;
  #pragma unroll
  for (int ks = 0; ks < 2; ks++) {
    bf16x8 aP[4], bV[4];
    #pragma unroll
    for (int mi = 0; mi < 4; mi++)
      aP[mi] = *(const bf16x8*)(&Ps[mi * 16 + lr][ks * 32 + g8]);
    #pragma unroll
    for (int ni = 0; ni < 4; ni++)
      #pragma unroll
      for (int j = 0; j < 8; j++)
        bV[ni][j] = *(const __bf16*)(vb + (size_t)(ks * 32 + g8 + j) * (2 * DIM_) + ni * 16 + lr);
    #pragma unroll
    for (int mi = 0; mi < 4; mi++)
      #pragma unroll
      for (int ni = 0; ni < 4; ni++)
        O[mi][ni] = __builtin_amdgcn_mfma_f32_16x16x32_bf16(aP[mi], bV[ni], O[mi][ni], 0, 0, 0);
  }
  WAVE_LDS_FENCE();                           // aP reads done -> Ps reusable for O

  #pragma unroll
  for (int mi = 0; mi < 4; mi++)
    #pragma unroll
    for (int ni = 0; ni < 4; ni++)
      #pragma unroll
      for (int r = 0; r < 4; r++)
        Ps[mi * 16 + g * 4 + r][ni * 16 + lr] = f2b(O[mi][ni][r] * vmul);
  WAVE_LDS_FENCE();
  uint4* dst = (uint4*)(ao + (size_t)(bn0 + lane) * DIM_ + h * HD_);
  #pragma unroll
  for (int c = 0; c < 8; c++)
    dst[c] = *(const uint4*)(&Ps[lane][c * 8]);
}

// ================= out-GEMM (256 blocks, 512t) =================
__global__ __launch_bounds__(512, 4) void gemm_out(const unsigned short* __restrict__ ao,
                                                   const unsigned short* __restrict__ wot,
                                                   unsigned short* __restrict__ C,
                                                   float* __restrict__ Cf,
                                                   const unsigned short* __restrict__ bias,
                                                   const void* __restrict__ text) {
  __shared__ __align__(16) unsigned char SMEM[73728];
  bool f32o = detect_isf((const unsigned short*)text, threadIdx.x);
  gemm256_core(ao, wot, C, Cf, bias, blockIdx.x, 32, B_ * N_, DIM_, DIM_, f32o,
               threadIdx.x, SMEM);
}

extern "C" void kernel_launch(void* const* d_in, const int* in_sizes, int n_in,
                              void* d_out, int out_size, void* d_ws, size_t ws_size,
                              hipStream_t stream) {
  const void* text = d_in[0];
  const void* media = d_in[1];
  const void* mloc = d_in[2];
  const void* wq  = d_in[3];
  const void* wkv = d_in[4];
  const void* wo  = d_in[5];
  const void* bo  = d_in[6];
  const void* lng = d_in[7];
  const void* lnb = d_in[8];

  char* ws = (char*)d_ws;
  const size_t OFF_TN   = (size_t)64 << 10;
  const size_t OFF_WQT  = OFF_TN  + ((size_t)16 << 20) + ((size_t)64 << 10);
  const size_t OFF_WKVT = OFF_WQT + ((size_t)2 << 20);
  const size_t OFF_WOT  = OFF_WKVT + ((size_t)4 << 20);
  const size_t OFF_KV   = OFF_WOT + ((size_t)2 << 20);
  const size_t OFF_MB   = OFF_KV  + ((size_t)8 << 20);
  const size_t OFF_BO   = OFF_MB  + ((size_t)4 << 20);
  const size_t OFF_AO   = OFF_BO  + ((size_t)64 << 10);
  int* tt               = (int*)(ws + 0);
  unsigned short* tn    = (unsigned short*)(ws + OFF_TN);
  unsigned short* wqt   = (unsigned short*)(ws + OFF_WQT);
  unsigned short* wkvt  = (unsigned short*)(ws + OFF_WKVT);
  unsigned short* wot   = (unsigned short*)(ws + OFF_WOT);
  unsigned short* kvb   = (unsigned short*)(ws + OFF_KV);
  unsigned short* mb    = (unsigned short*)(ws + OFF_MB);
  unsigned short* bob   = (unsigned short*)(ws + OFF_BO);
  unsigned short* ao    = (unsigned short*)(ws + OFF_AO);

  // L1: kv prerequisites (media cast, wkv transpose) + bo cast
  prep1_kernel<<<4097, 256, 0, stream>>>(text, media, mb, bo, bob, wkv, wkvt);
  // L2: times + kv-GEMM + LN + wq/wo transposes (kv overlaps memory-bound blocks)
  prep2_kernel<<<3204, 512, 0, stream>>>(text, mloc, tt, lng, lnb, tn,
                                         mb, wkvt, kvb, wq, wqt, wo, wot);
  // L3: fused q-GEMM + attention (per-wave 1:1 task mapping; no qb round-trip)
  qattn_kernel<<<256, 512, 0, stream>>>(tn, wqt, kvb, tt, ao);
  // L4: out = ao @ wo + bo
  gemm_out<<<256, 512, 0, stream>>>(ao, wot, (unsigned short*)d_out, (float*)d_out,
                                    bob, text);
}